// Round 3
// baseline (517.062 us; speedup 1.0000x reference)
//
#include <hip/hip_runtime.h>

// Shapes: S=128, I=J=512, CM=256, C=D=32, CZ=128. Output [1,512,512,128] fp32.
#define EPS 1e-5f

typedef _Float16 half8 __attribute__((ext_vector_type(8)));
typedef _Float16 half4 __attribute__((ext_vector_type(4)));
typedef float f32x4 __attribute__((ext_vector_type(4)));

// a/b workspace layout: [2 k-chunks][16384 (i*32+c) rows][72 halves]; cols 0..63 = s_loc, 64..71 pad.
#define AB_STRIDE 72
#define AB_CHUNK  (16384 * AB_STRIDE)

__device__ __forceinline__ void load16_to_lds(const void* g, void* l) {
    __builtin_amdgcn_global_load_lds((__attribute__((address_space(1))) void*)g,
                                     (__attribute__((address_space(3))) void*)l, 16, 0, 0);
}

// ---------------- cvt kernel: WoH (fp16, K permuted to k'=d*32+c) + WabH (fp16) ----------------
__global__ void k_cvt(const float* __restrict__ Wo, const float* __restrict__ Wa,
                      const float* __restrict__ Wb, _Float16* __restrict__ WoH,
                      _Float16* __restrict__ WabH)
{
    int t = blockIdx.x * 256 + threadIdx.x;     // 144 blocks -> 36864 threads
    if (t < 32768) {
        int n  = t >> 8;
        int k4 = (t & 255) * 4;                 // k = c*32 + d ; 4 consecutive d, same c
        float4 v = *(const float4*)(Wo + (size_t)n * 1024 + k4);
        int c = k4 >> 5, d0 = k4 & 31;
        _Float16* dst = WoH + (size_t)n * 1024 + c;
        dst[(d0 + 0) * 32] = (_Float16)v.x;
        dst[(d0 + 1) * 32] = (_Float16)v.y;
        dst[(d0 + 2) * 32] = (_Float16)v.z;
        dst[(d0 + 3) * 32] = (_Float16)v.w;
    } else {
        int idx = (t - 32768) * 4;              // 16384 elems: rows 0..31 Wa, 32..63 Wb
        const float* src = (idx < 8192) ? (Wa + idx) : (Wb + (idx - 8192));
        float4 v = *(const float4*)src;
        half4 h;
        h[0] = (_Float16)v.x; h[1] = (_Float16)v.y; h[2] = (_Float16)v.z; h[3] = (_Float16)v.w;
        *(half4*)(WabH + idx) = h;
    }
}

// ---------------- Kernel 1: LN + A/B projection ----------------
// 1024 blocks x 512 threads. Block: 4 i values x 16 s values. 2 barriers, 3 blocks/CU.
__global__ __launch_bounds__(512, 6)
void k1_ln_proj(const float* __restrict__ x, const float* __restrict__ nw,
                const float* __restrict__ nb, const _Float16* __restrict__ WabH,
                _Float16* __restrict__ aT, _Float16* __restrict__ bT)
{
    __shared__ _Float16 xln[64 * 264];   // 33792 B; rows rl = s_l*4 + i_l
    __shared__ _Float16 oT[256 * 24];    // 12288 B; rows 0..127 a (i_l*32+c), 128..255 b; 16 s cols + pad

    const int tid  = threadIdx.x;
    const int lane = tid & 63;
    const int w    = tid >> 6;
    const int quad = lane >> 4;
    const int l15  = lane & 15;

    const int i0   = (blockIdx.x >> 3) * 4;     // 128 i-groups
    const int s16  = blockIdx.x & 7;            // 8 s-chunks of 16
    const int ck   = s16 >> 2;                  // K-chunk in aT/bT
    const int col0 = (s16 & 3) * 16;            // column offset inside 64-col chunk

    // LN: 8 rows per wave
    #pragma unroll
    for (int rr = 0; rr < 8; ++rr) {
        int rl = w * 8 + rr;                    // rl = s_l*4 + i_l
        int s_ = s16 * 16 + (rl >> 2);
        int i_ = i0 + (rl & 3);
        const float4* xr = (const float4*)(x + ((size_t)s_ * 512 + i_) * 256);
        float4 v = xr[lane];
        float sum = v.x + v.y + v.z + v.w;
        float ss  = v.x * v.x + v.y * v.y + v.z * v.z + v.w * v.w;
        #pragma unroll
        for (int off = 32; off > 0; off >>= 1) {
            sum += __shfl_xor(sum, off);
            ss  += __shfl_xor(ss, off);
        }
        float mu  = sum * (1.f / 256.f);
        float var = ss * (1.f / 256.f) - mu * mu;
        float rs  = rsqrtf(var + EPS);
        float4 gw = ((const float4*)nw)[lane];
        float4 gb = ((const float4*)nb)[lane];
        half4 o;
        o[0] = (_Float16)((v.x - mu) * rs * gw.x + gb.x);
        o[1] = (_Float16)((v.y - mu) * rs * gw.y + gb.y);
        o[2] = (_Float16)((v.z - mu) * rs * gw.z + gb.z);
        o[3] = (_Float16)((v.w - mu) * rs * gw.w + gb.w);
        *(half4*)(xln + rl * 264 + lane * 4) = o;
    }
    __syncthreads();

    // GEMM 64x64x256: wave -> M-tile mt = w&3, N-tiles (w>>2)*32 + {0,16}; B from global (L2-hot)
    const int mt = w & 3, ntg = w >> 2;
    f32x4 acc2[2] = {};
    #pragma unroll
    for (int kk = 0; kk < 8; ++kk) {
        half8 af = *(const half8*)(xln + (mt * 16 + l15) * 264 + kk * 32 + quad * 8);
        #pragma unroll
        for (int t = 0; t < 2; ++t) {
            half8 bf = *(const half8*)(WabH + (ntg * 32 + t * 16 + l15) * 256 + kk * 32 + quad * 8);
            acc2[t] = __builtin_amdgcn_mfma_f32_16x16x32_f16(af, bf, acc2[t], 0, 0, 0);
        }
    }

    // transform: D[m][n]: m = mt*16+quad*4+r -> s_l = mt*4+quad, i_l = r; n -> c64
    #pragma unroll
    for (int t = 0; t < 2; ++t) {
        int c64  = ntg * 32 + t * 16 + l15;
        int base = ((c64 >= 32) ? 128 : 0) + (c64 & 31);
        int s_l  = mt * 4 + quad;
        #pragma unroll
        for (int r = 0; r < 4; ++r)
            oT[(base + r * 32) * 24 + s_l] = (_Float16)acc2[t][r];
    }
    __syncthreads();

    // store: 512 units = 256 rows x 2 half8
    {
        int row = tid >> 1, h = tid & 1;
        half8 v = *(const half8*)(oT + row * 24 + h * 8);
        _Float16* dst = (row < 128) ? aT : bT;
        int grow = i0 * 32 + (row & 127);
        *(half8*)(dst + (size_t)ck * AB_CHUNK + (size_t)grow * 72 + col0 + h * 8) = v;
    }
}

// ---------------- Kernel 2: fused outer-product-mean + Wo projection ----------------
// 8192 blocks x 512 threads, patch-swizzled. Per block: 8 i x 4 j.
__global__ __launch_bounds__(512, 4)
void k2_main(const _Float16* __restrict__ aT, const _Float16* __restrict__ bT,
             const _Float16* __restrict__ WoH, const float* __restrict__ bo,
             float* __restrict__ out)
{
    __shared__ _Float16 smem[33024];               // 66048 B
    _Float16* sA = smem;                           // 256 rows x 72
    _Float16* sB = smem + 256 * AB_STRIDE;         // 128 rows x 72
    _Float16* oL = smem;                           // 32 pairs x 1032 (overlaps after phase 1)

    const int tid  = threadIdx.x;
    const int lane = tid & 63;
    const int w    = tid >> 6;
    const int quad = lane >> 4;
    const int l15  = lane & 15;
    const int wy   = w >> 1, wx = w & 1;

    // patch swizzle: 128-block patches cover 16 jt x 8 it (~1.2 MB working set -> L2-local)
    const int bid    = blockIdx.x;
    const int patch  = bid >> 7, within = bid & 127;
    const int jt = ((patch & 7) << 4) | (within & 15);
    const int it = ((patch >> 3) << 3) | (within >> 4);

    // issue first Wo prefetch group immediately (in flight during phase 1)
    const int n0 = w * 16 + l15;
    const _Float16* wp = WoH + (size_t)n0 * 1024 + quad * 8;
    half8 wreg[2][4];
    #pragma unroll
    for (int u = 0; u < 4; ++u) wreg[0][u] = *(const half8*)(wp + u * 32);
    const float bias = bo[n0];

    const char* gA = (const char*)(aT + (size_t)it * 256 * AB_STRIDE);
    const char* gB = (const char*)(bT + (size_t)jt * 128 * AB_STRIDE);

    f32x4 acc[4][4] = {};

    for (int ck = 0; ck < 2; ++ck) {
        // stage: sA 36 segs + sB 18 segs of 1024 B
        const char* cA = gA + (size_t)ck * (AB_CHUNK * 2);
        const char* cB = gB + (size_t)ck * (AB_CHUNK * 2);
        for (int seg = w; seg < 54; seg += 8) {
            if (seg < 36) load16_to_lds(cA + seg * 1024 + lane * 16, (char*)sA + seg * 1024 + lane * 16);
            else          load16_to_lds(cB + (seg - 36) * 1024 + lane * 16, (char*)sB + (seg - 36) * 1024 + lane * 16);
        }
        __syncthreads();

        #pragma unroll
        for (int kloc = 0; kloc < 2; ++kloc) {
            half8 af[4], bf[4];
            #pragma unroll
            for (int mt = 0; mt < 4; ++mt)
                af[mt] = *(const half8*)(sA + (wy * 64 + mt * 16 + l15) * AB_STRIDE + kloc * 32 + quad * 8);
            #pragma unroll
            for (int nt = 0; nt < 4; ++nt)
                bf[nt] = *(const half8*)(sB + (wx * 64 + nt * 16 + l15) * AB_STRIDE + kloc * 32 + quad * 8);
            #pragma unroll
            for (int mt = 0; mt < 4; ++mt)
                #pragma unroll
                for (int nt = 0; nt < 4; ++nt)
                    acc[mt][nt] = __builtin_amdgcn_mfma_f32_16x16x32_f16(af[mt], bf[nt], acc[mt][nt], 0, 0, 0);
        }
        __syncthreads();
    }

    // C/D -> A-operand transform into oL[pair][k'=d*32+c], XOR-swizzled 16B chunks.
    #pragma unroll
    for (int mt = 0; mt < 4; ++mt) {
        int c0     = (mt & 1) * 16 + quad * 4;
        int chunk3 = (c0 >> 3);
        int il     = wy * 2 + (mt >> 1);
        #pragma unroll
        for (int nt = 0; nt < 4; ++nt) {
            int d    = (nt & 1) * 16 + l15;
            int jl   = wx * 2 + (nt >> 1);
            int pair = il * 4 + jl;
            int cS   = (c0 & 7) + ((chunk3 ^ ((d >> 1) & 3)) << 3);   // swizzled c
            half4 v;
            v[0] = (_Float16)(acc[mt][nt][0] * (1.f / 128.f));
            v[1] = (_Float16)(acc[mt][nt][1] * (1.f / 128.f));
            v[2] = (_Float16)(acc[mt][nt][2] * (1.f / 128.f));
            v[3] = (_Float16)(acc[mt][nt][3] * (1.f / 128.f));
            *(half4*)(oL + pair * 1032 + d * 32 + cS) = v;
        }
    }
    __syncthreads();

    // Phase 2: wave w -> N cols [w*16, w*16+16), M = 32 pairs, K = 1024.
    // Software-pipelined Wo prefetch, depth 4.
    f32x4 zacc[2] = {};
    #pragma unroll
    for (int g = 0; g < 8; ++g) {
        int cur = g & 1;
        if (g < 7) {
            #pragma unroll
            for (int u = 0; u < 4; ++u)
                wreg[cur ^ 1][u] = *(const half8*)(wp + (g + 1) * 128 + u * 32);
        }
        #pragma unroll
        for (int u = 0; u < 4; ++u) {
            int kk  = g * 4 + u;
            int csw = (quad ^ ((kk >> 1) & 3)) * 8;    // un-swizzle chunk
            half8 oa0 = *(const half8*)(oL + l15 * 1032 + kk * 32 + csw);
            half8 oa1 = *(const half8*)(oL + (16 + l15) * 1032 + kk * 32 + csw);
            zacc[0] = __builtin_amdgcn_mfma_f32_16x16x32_f16(oa0, wreg[cur][u], zacc[0], 0, 0, 0);
            zacc[1] = __builtin_amdgcn_mfma_f32_16x16x32_f16(oa1, wreg[cur][u], zacc[1], 0, 0, 0);
        }
    }

    // epilogue: pair = mt2*16+quad*4+r -> il = mt2*4+quad, jl = r ; n = w*16+l15
    #pragma unroll
    for (int mt2 = 0; mt2 < 2; ++mt2) {
        #pragma unroll
        for (int r = 0; r < 4; ++r) {
            int il = mt2 * 4 + quad;
            int jl = r;
            out[(((size_t)(it * 8 + il)) * 512 + jt * 4 + jl) * 128 + n0 - l15 + l15] = zacc[mt2][r] + bias;
        }
    }
}

extern "C" void kernel_launch(void* const* d_in, const int* in_sizes, int n_in,
                              void* d_out, int out_size, void* d_ws, size_t ws_size,
                              hipStream_t stream)
{
    const float* x      = (const float*)d_in[0];
    const float* norm_w = (const float*)d_in[1];
    const float* norm_b = (const float*)d_in[2];
    const float* Wa     = (const float*)d_in[3];
    const float* Wb     = (const float*)d_in[4];
    const float* Wo     = (const float*)d_in[5];
    const float* bo     = (const float*)d_in[6];
    float* out = (float*)d_out;

    _Float16* aT   = (_Float16*)d_ws;                      // 2*16384*72
    _Float16* bT   = aT + 2 * (size_t)AB_CHUNK;
    _Float16* WoH  = bT + 2 * (size_t)AB_CHUNK;            // 131072
    _Float16* WabH = WoH + 131072;                         // 16384

    k_cvt<<<144, 256, 0, stream>>>(Wo, Wa, Wb, WoH, WabH);
    k1_ln_proj<<<1024, 512, 0, stream>>>(x, norm_w, norm_b, WabH, aT, bT);
    k2_main<<<8192, 512, 0, stream>>>(aT, bT, WoH, bo, out);
}

// Round 5
// 496.625 us; speedup vs baseline: 1.0412x; 1.0412x over previous
//
#include <hip/hip_runtime.h>

// Shapes: S=128, I=J=512, CM=256, C=D=32, CZ=128. Output [1,512,512,128] fp32.
#define EPS 1e-5f

typedef _Float16 half8 __attribute__((ext_vector_type(8)));
typedef _Float16 half4 __attribute__((ext_vector_type(4)));
typedef float f32x4 __attribute__((ext_vector_type(4)));

// a/b workspace layout: [2 k-chunks][16384 (i*32+c) rows][72 halves]; cols 0..63 = s_loc, 64..71 pad.
#define AB_STRIDE 72
#define AB_CHUNK  (16384 * AB_STRIDE)

__device__ __forceinline__ void load16_to_lds(const void* g, void* l) {
    __builtin_amdgcn_global_load_lds((__attribute__((address_space(1))) void*)g,
                                     (__attribute__((address_space(3))) void*)l, 16, 0, 0);
}

// ---------------- Kernel 1: LN + A/B projection + embedded weight conversions ----------------
// 1024 blocks x 512 threads, 2 blocks/CU. Block: 4 i values x 16 s values.
__global__ __launch_bounds__(512, 4)
void k1_ln_proj(const float* __restrict__ x, const float* __restrict__ nw,
                const float* __restrict__ nb, const float* __restrict__ Wa,
                const float* __restrict__ Wb, const float* __restrict__ Wo,
                _Float16* __restrict__ aT, _Float16* __restrict__ bT,
                _Float16* __restrict__ WoH)
{
    __shared__ _Float16 xln[64 * 264];   // 33792 B; rows rl = s_l*4 + i_l
    __shared__ _Float16 Wab[64 * 264];   // 33792 B; rows 0..31 Wa, 32..63 Wb
    __shared__ _Float16 oT[256 * 24];    // 12288 B; rows 0..127 a (i_l*32+c), 128..255 b

    const int tid  = threadIdx.x;
    const int lane = tid & 63;
    const int w    = tid >> 6;
    const int quad = lane >> 4;
    const int l15  = lane & 15;

    const int i0   = (blockIdx.x >> 3) * 4;     // 128 i-groups
    const int s16  = blockIdx.x & 7;            // 8 s-chunks of 16
    const int ck   = s16 >> 2;                  // K-chunk in aT/bT
    const int col0 = (s16 & 3) * 16;            // column offset inside 64-col chunk

    // WoH conversion, distributed: blocks 0..127 convert 1024 Wo elems each (k permuted to k'=d*32+c)
    if (blockIdx.x < 128 && tid < 256) {
        int idx = blockIdx.x * 1024 + tid * 4;          // covers all 131072 elements
        float4 v = *(const float4*)(Wo + idx);
        int n = idx >> 10, k = idx & 1023;
        int c = k >> 5, d0 = k & 31;
        _Float16* dst = WoH + (size_t)n * 1024 + c;
        dst[(d0 + 0) * 32] = (_Float16)v.x;
        dst[(d0 + 1) * 32] = (_Float16)v.y;
        dst[(d0 + 2) * 32] = (_Float16)v.z;
        dst[(d0 + 3) * 32] = (_Float16)v.w;
    }

    // Wa/Wb fp32 -> fp16 LDS (each block loads the 64 KB; L2-hot after first wave of blocks)
    #pragma unroll
    for (int u = 0; u < 8; ++u) {
        int e4 = (u * 512 + tid) * 4;           // 0..16383, 4-aligned
        const float* src = (e4 < 8192) ? (Wa + e4) : (Wb + (e4 - 8192));
        float4 v = *(const float4*)src;
        half4 h;
        h[0] = (_Float16)v.x; h[1] = (_Float16)v.y; h[2] = (_Float16)v.z; h[3] = (_Float16)v.w;
        int r = e4 >> 8, m = e4 & 255;
        *(half4*)(Wab + r * 264 + m) = h;
    }

    // LN: 8 rows per wave
    #pragma unroll
    for (int rr = 0; rr < 8; ++rr) {
        int rl = w * 8 + rr;                    // rl = s_l*4 + i_l
        int s_ = s16 * 16 + (rl >> 2);
        int i_ = i0 + (rl & 3);
        const float4* xr = (const float4*)(x + ((size_t)s_ * 512 + i_) * 256);
        float4 v = xr[lane];
        float sum = v.x + v.y + v.z + v.w;
        float ss  = v.x * v.x + v.y * v.y + v.z * v.z + v.w * v.w;
        #pragma unroll
        for (int off = 32; off > 0; off >>= 1) {
            sum += __shfl_xor(sum, off);
            ss  += __shfl_xor(ss, off);
        }
        float mu  = sum * (1.f / 256.f);
        float var = ss * (1.f / 256.f) - mu * mu;
        float rs  = rsqrtf(var + EPS);
        float4 gw = ((const float4*)nw)[lane];
        float4 gb = ((const float4*)nb)[lane];
        half4 o;
        o[0] = (_Float16)((v.x - mu) * rs * gw.x + gb.x);
        o[1] = (_Float16)((v.y - mu) * rs * gw.y + gb.y);
        o[2] = (_Float16)((v.z - mu) * rs * gw.z + gb.z);
        o[3] = (_Float16)((v.w - mu) * rs * gw.w + gb.w);
        *(half4*)(xln + rl * 264 + lane * 4) = o;
    }
    __syncthreads();

    // GEMM 64x64x256: wave -> M-tile mt = w&3, N-tiles (w>>2)*32 + {0,16}; B from LDS
    const int mt = w & 3, ntg = w >> 2;
    f32x4 acc2[2] = {};
    #pragma unroll
    for (int kk = 0; kk < 8; ++kk) {
        half8 af = *(const half8*)(xln + (mt * 16 + l15) * 264 + kk * 32 + quad * 8);
        #pragma unroll
        for (int t = 0; t < 2; ++t) {
            half8 bf = *(const half8*)(Wab + (ntg * 32 + t * 16 + l15) * 264 + kk * 32 + quad * 8);
            acc2[t] = __builtin_amdgcn_mfma_f32_16x16x32_f16(af, bf, acc2[t], 0, 0, 0);
        }
    }

    // transform: D[m][n]: m = mt*16+quad*4+r -> s_l = mt*4+quad, i_l = r; n -> c64
    #pragma unroll
    for (int t = 0; t < 2; ++t) {
        int c64  = ntg * 32 + t * 16 + l15;
        int base = ((c64 >= 32) ? 128 : 0) + (c64 & 31);
        int s_l  = mt * 4 + quad;
        #pragma unroll
        for (int r = 0; r < 4; ++r)
            oT[(base + r * 32) * 24 + s_l] = (_Float16)acc2[t][r];
    }
    __syncthreads();

    // store: 512 units = 256 rows x 2 half8
    {
        int row = tid >> 1, h = tid & 1;
        half8 v = *(const half8*)(oT + row * 24 + h * 8);
        _Float16* dst = (row < 128) ? aT : bT;
        int grow = i0 * 32 + (row & 127);
        *(half8*)(dst + (size_t)ck * AB_CHUNK + (size_t)grow * 72 + col0 + h * 8) = v;
    }
}

// ---------------- Kernel 2: fused outer-product-mean + Wo projection ----------------
// 8192 blocks x 512 threads, patch-swizzled. Per block: 8 i x 4 j. (spill-free: 64+64 regs)
__global__ __launch_bounds__(512, 4)
void k2_main(const _Float16* __restrict__ aT, const _Float16* __restrict__ bT,
             const _Float16* __restrict__ WoH, const float* __restrict__ bo,
             float* __restrict__ out)
{
    __shared__ _Float16 smem[33024];               // 66048 B
    _Float16* sA = smem;                           // 256 rows x 72
    _Float16* sB = smem + 256 * AB_STRIDE;         // 128 rows x 72
    _Float16* oL = smem;                           // 32 pairs x 1032 (overlaps after phase 1)

    const int tid  = threadIdx.x;
    const int lane = tid & 63;
    const int w    = tid >> 6;
    const int quad = lane >> 4;
    const int l15  = lane & 15;
    const int wy   = w >> 1, wx = w & 1;

    // patch swizzle: 128-block patches cover 16 jt x 8 it (~1.2 MB working set -> L2-local)
    const int bid    = blockIdx.x;
    const int patch  = bid >> 7, within = bid & 127;
    const int jt = ((patch & 7) << 4) | (within & 15);
    const int it = ((patch >> 3) << 3) | (within >> 4);

    const char* gA = (const char*)(aT + (size_t)it * 256 * AB_STRIDE);
    const char* gB = (const char*)(bT + (size_t)jt * 128 * AB_STRIDE);

    f32x4 acc[4][4] = {};

    for (int ck = 0; ck < 2; ++ck) {
        // stage: sA 36 segs + sB 18 segs of 1024 B
        const char* cA = gA + (size_t)ck * (AB_CHUNK * 2);
        const char* cB = gB + (size_t)ck * (AB_CHUNK * 2);
        for (int seg = w; seg < 54; seg += 8) {
            if (seg < 36) load16_to_lds(cA + seg * 1024 + lane * 16, (char*)sA + seg * 1024 + lane * 16);
            else          load16_to_lds(cB + (seg - 36) * 1024 + lane * 16, (char*)sB + (seg - 36) * 1024 + lane * 16);
        }
        __syncthreads();

        #pragma unroll
        for (int kloc = 0; kloc < 2; ++kloc) {
            half8 af[4], bf[4];
            #pragma unroll
            for (int mt = 0; mt < 4; ++mt)
                af[mt] = *(const half8*)(sA + (wy * 64 + mt * 16 + l15) * AB_STRIDE + kloc * 32 + quad * 8);
            #pragma unroll
            for (int nt = 0; nt < 4; ++nt)
                bf[nt] = *(const half8*)(sB + (wx * 64 + nt * 16 + l15) * AB_STRIDE + kloc * 32 + quad * 8);
            #pragma unroll
            for (int mt = 0; mt < 4; ++mt)
                #pragma unroll
                for (int nt = 0; nt < 4; ++nt)
                    acc[mt][nt] = __builtin_amdgcn_mfma_f32_16x16x32_f16(af[mt], bf[nt], acc[mt][nt], 0, 0, 0);
        }
        __syncthreads();
    }

    // C/D -> A-operand transform into oL[pair][k'=d*32+c], XOR-swizzled 16B chunks.
    #pragma unroll
    for (int mt = 0; mt < 4; ++mt) {
        int c0     = (mt & 1) * 16 + quad * 4;
        int chunk3 = (c0 >> 3);
        int il     = wy * 2 + (mt >> 1);
        #pragma unroll
        for (int nt = 0; nt < 4; ++nt) {
            int d    = (nt & 1) * 16 + l15;
            int jl   = wx * 2 + (nt >> 1);
            int pair = il * 4 + jl;
            int cS   = (c0 & 7) + ((chunk3 ^ ((d >> 1) & 3)) << 3);   // swizzled c
            half4 v;
            v[0] = (_Float16)(acc[mt][nt][0] * (1.f / 128.f));
            v[1] = (_Float16)(acc[mt][nt][1] * (1.f / 128.f));
            v[2] = (_Float16)(acc[mt][nt][2] * (1.f / 128.f));
            v[3] = (_Float16)(acc[mt][nt][3] * (1.f / 128.f));
            *(half4*)(oL + pair * 1032 + d * 32 + cS) = v;
        }
    }
    __syncthreads();

    // Phase 2: wave w -> N cols [w*16, w*16+16), M = 32 pairs, K = 1024 (spill-free form)
    f32x4 zacc[2] = {};
    const int n0 = w * 16 + l15;
    #pragma unroll 4
    for (int kk = 0; kk < 32; ++kk) {
        int csw = (quad ^ ((kk >> 1) & 3)) * 8;    // un-swizzle chunk
        half8 oa0 = *(const half8*)(oL + l15 * 1032 + kk * 32 + csw);
        half8 oa1 = *(const half8*)(oL + (16 + l15) * 1032 + kk * 32 + csw);
        half8 w0  = *(const half8*)(WoH + (size_t)n0 * 1024 + kk * 32 + quad * 8);
        zacc[0] = __builtin_amdgcn_mfma_f32_16x16x32_f16(oa0, w0, zacc[0], 0, 0, 0);
        zacc[1] = __builtin_amdgcn_mfma_f32_16x16x32_f16(oa1, w0, zacc[1], 0, 0, 0);
    }

    // epilogue: pair = mt2*16+quad*4+r -> il = mt2*4+quad, jl = r ; n = w*16+l15
    float bias = bo[n0];
    #pragma unroll
    for (int mt2 = 0; mt2 < 2; ++mt2) {
        #pragma unroll
        for (int r = 0; r < 4; ++r) {
            int il = mt2 * 4 + quad;
            int jl = r;
            out[(((size_t)(it * 8 + il)) * 512 + jt * 4 + jl) * 128 + n0] = zacc[mt2][r] + bias;
        }
    }
}

extern "C" void kernel_launch(void* const* d_in, const int* in_sizes, int n_in,
                              void* d_out, int out_size, void* d_ws, size_t ws_size,
                              hipStream_t stream)
{
    const float* x      = (const float*)d_in[0];
    const float* norm_w = (const float*)d_in[1];
    const float* norm_b = (const float*)d_in[2];
    const float* Wa     = (const float*)d_in[3];
    const float* Wb     = (const float*)d_in[4];
    const float* Wo     = (const float*)d_in[5];
    const float* bo     = (const float*)d_in[6];
    float* out = (float*)d_out;

    _Float16* aT   = (_Float16*)d_ws;                      // 2*16384*72
    _Float16* bT   = aT + 2 * (size_t)AB_CHUNK;
    _Float16* WoH  = bT + 2 * (size_t)AB_CHUNK;            // 131072 halves

    k1_ln_proj<<<1024, 512, 0, stream>>>(x, norm_w, norm_b, Wa, Wb, Wo, aT, bT, WoH);
    k2_main<<<8192, 512, 0, stream>>>(aT, bT, WoH, bo, out);
}